// Round 1
// baseline (219.288 us; speedup 1.0000x reference)
//
#include <hip/hip_runtime.h>
#include <hip/hip_bf16.h>

typedef unsigned long long u64;

#define MAXD 5  // MAX_DIST

// ---------------------------------------------------------------------------
// Multi-source BFS with <=64 sources packed as a uint64 bitmask per node.
// ws layout: V[N] | F[N] | NF[N] | CNT[N] (u64 each) | nvalid (int)
//   V   : visited mask
//   F   : current frontier mask (nodes first reached at previous depth)
//   NF  : next-frontier scatter target (atomicOr)
//   CNT : packed per-depth popcounts, byte d = #sources first reaching node at depth d
// ---------------------------------------------------------------------------

__global__ void zero_ws(u64* __restrict__ p, size_t n) {
    size_t i = (size_t)blockIdx.x * blockDim.x + threadIdx.x;
    size_t stride = (size_t)gridDim.x * blockDim.x;
    for (; i < n; i += stride) p[i] = 0ull;
}

// One wave (64 threads). Gathers the 2*A anchor entities, dedups O(K^2),
// assigns bit i to each unique source, writes initial F/V/CNT + n_valid.
__global__ void setup_sources(const int* __restrict__ h, const int* __restrict__ t,
                              const int* __restrict__ anchor, int A,
                              u64* __restrict__ F, u64* __restrict__ V,
                              u64* __restrict__ cnt, int* __restrict__ nvalid) {
    __shared__ int ents[64];
    int i = threadIdx.x;
    int K = 2 * A;  // 64
    if (i < K) {
        int a = anchor[(i < A) ? i : (i - A)];
        ents[i] = (i < A) ? h[a] : t[a];
    }
    __syncthreads();
    bool uniq = false;
    int my = -1;
    if (i < K) {
        my = ents[i];
        uniq = true;
        for (int j = 0; j < i; ++j) {
            if (ents[j] == my) { uniq = false; break; }
        }
    }
    u64 mask = __ballot(uniq);
    if (i == 0) *nvalid = (int)__popcll(mask);
    if (uniq) {
        // unique entity ids are distinct addresses -> plain stores are race-free
        u64 bit = 1ull << i;
        F[my] = bit;
        V[my] = bit;
        cnt[my] = 1ull;  // depth-0 count = 1 (byte 0)
    }
}

// One BFS level: scatter frontier masks across edges (both directions).
__global__ void edge_prop(const int* __restrict__ h, const int* __restrict__ t,
                          const u64* __restrict__ F, u64* __restrict__ NF, int E) {
    int e = blockIdx.x * blockDim.x + threadIdx.x;
    if (e >= E) return;
    int u = h[e], v = t[e];
    u64 fu = F[u];
    u64 fv = F[v];
    if (fu) atomicOr(&NF[v], fu);
    if (fv) atomicOr(&NF[u], fv);
}

// newly = NF & ~V; record popcount at this depth; advance frontier; clear NF.
__global__ void node_update(u64* __restrict__ F, u64* __restrict__ NF,
                            u64* __restrict__ V, u64* __restrict__ cnt,
                            int N, int depth) {
    int n = blockIdx.x * blockDim.x + threadIdx.x;
    if (n >= N) return;
    u64 nf = NF[n];
    NF[n] = 0ull;
    u64 vis = V[n];
    u64 newly = nf & ~vis;
    F[n] = newly;
    if (newly) {
        V[n] = vis | newly;
        cnt[n] += (u64)__popcll(newly) << (8 * depth);
    }
}

// out[n][j] = (sum_{d=0..4} c_d * E[d][j] + (nv - sum c_d) * E[5][j]) / nv
__global__ void finalize(const u64* __restrict__ cnt, const int* __restrict__ nvalid,
                         const float* __restrict__ embed, float* __restrict__ out,
                         int N, int D) {
    int idx = blockIdx.x * blockDim.x + threadIdx.x;
    if (idx >= N * D) return;
    int n = idx >> 4;          // D == 16
    int j = idx & 15;
    u64 c = cnt[n];
    int nv = *nvalid;
    float inv = 1.0f / (float)(nv > 0 ? nv : 1);
    float acc = 0.0f;
    int total = 0;
#pragma unroll
    for (int d = 0; d < MAXD; ++d) {
        int cd = (int)((c >> (8 * d)) & 0xffull);
        total += cd;
        acc += (float)cd * embed[d * D + j];
    }
    int c5 = nv - total;  // dist==5: reached at depth 5 OR never reached
    acc += (float)c5 * embed[MAXD * D + j];
    out[idx] = acc * inv;
}

extern "C" void kernel_launch(void* const* d_in, const int* in_sizes, int n_in,
                              void* d_out, int out_size, void* d_ws, size_t ws_size,
                              hipStream_t stream) {
    const int*   h      = (const int*)d_in[0];
    const int*   t      = (const int*)d_in[1];
    const int*   anchor = (const int*)d_in[2];
    const float* embed  = (const float*)d_in[4];
    float*       out    = (float*)d_out;

    int E = in_sizes[0];
    int A = in_sizes[2];                    // 32 anchor triples -> K = 64 sources
    int D = in_sizes[4] / (MAXD + 1);       // 16
    int N = out_size / D;                   // 50000

    u64* V   = (u64*)d_ws;
    u64* F   = V + N;
    u64* NF  = F + N;
    u64* CNT = NF + N;
    int* nvalid = (int*)(CNT + N);

    // d_ws is re-poisoned to 0xAA before every call -> must zero our state.
    zero_ws<<<512, 256, 0, stream>>>((u64*)d_ws, (size_t)4 * N);
    setup_sources<<<1, 64, 0, stream>>>(h, t, anchor, A, F, V, CNT, nvalid);

    int eb = (E + 255) / 256;
    int nb = (N + 255) / 256;
    for (int depth = 1; depth <= MAXD - 1; ++depth) {  // depth-5 folds into c5
        edge_prop<<<eb, 256, 0, stream>>>(h, t, F, NF, E);
        node_update<<<nb, 256, 0, stream>>>(F, NF, V, CNT, N, depth);
    }

    int ob = (N * D + 255) / 256;
    finalize<<<ob, 256, 0, stream>>>(CNT, nvalid, embed, out, N, D);
}

// Round 2
// 215.651 us; speedup vs baseline: 1.0169x; 1.0169x over previous
//
#include <hip/hip_runtime.h>
#include <hip/hip_bf16.h>

typedef unsigned long long u64;

#define MAXD 5   // MAX_DIST
#define NXCD 8   // XCDs on MI355X

// ---------------------------------------------------------------------------
// Multi-source BFS, <=64 sources packed in a u64 bitmask per node.
// Device-scope atomics cost a 32B MALL write-through each (measured: 51 MB /
// edge pass). Instead: 8 per-XCD private next-frontier copies updated with
// workgroup-scope atomicOr (executes in the local XCD L2, cached line),
// merged in node_update after the kernel boundary.
//
// ws layout (u64 each): V[N] | F[N] | CNT[N] | NF8[8*N] | nvalid(int)
// ---------------------------------------------------------------------------

__device__ __forceinline__ int xcc_id() {
    int x;
    asm volatile("s_getreg_b32 %0, hwreg(HW_REG_XCC_ID)" : "=s"(x));
    return x & (NXCD - 1);
}

__global__ void zero_ws(u64* __restrict__ p, size_t n) {
    size_t i = (size_t)blockIdx.x * blockDim.x + threadIdx.x;
    size_t stride = (size_t)gridDim.x * blockDim.x;
    for (; i < n; i += stride) p[i] = 0ull;
}

// One wave. Gather 2*A anchor entities, dedup O(K^2), assign bit i to each
// unique source, write initial F/V/CNT + n_valid.
__global__ void setup_sources(const int* __restrict__ h, const int* __restrict__ t,
                              const int* __restrict__ anchor, int A,
                              u64* __restrict__ F, u64* __restrict__ V,
                              u64* __restrict__ cnt, int* __restrict__ nvalid) {
    __shared__ int ents[64];
    int i = threadIdx.x;
    int K = 2 * A;  // 64
    if (i < K) {
        int a = anchor[(i < A) ? i : (i - A)];
        ents[i] = (i < A) ? h[a] : t[a];
    }
    __syncthreads();
    bool uniq = false;
    int my = -1;
    if (i < K) {
        my = ents[i];
        uniq = true;
        for (int j = 0; j < i; ++j) {
            if (ents[j] == my) { uniq = false; break; }
        }
    }
    u64 mask = __ballot(uniq);
    if (i == 0) *nvalid = (int)__popcll(mask);
    if (uniq) {
        u64 bit = 1ull << i;
        F[my] = bit;       // distinct addresses -> race-free plain stores
        V[my] = bit;
        cnt[my] = 1ull;    // depth-0 count (byte 0)
    }
}

// One BFS level: scatter frontier masks across edges (both directions) into
// this XCD's private NF copy with L2-local (workgroup-scope) atomics.
__global__ void edge_prop(const int* __restrict__ h, const int* __restrict__ t,
                          const u64* __restrict__ F, u64* __restrict__ NF8,
                          int N, int E) {
    u64* __restrict__ NF = NF8 + (size_t)xcc_id() * N;
    int e = blockIdx.x * blockDim.x + threadIdx.x;
    if (e >= E) return;
    int u = h[e], v = t[e];
    u64 fu = F[u];
    u64 fv = F[v];
    if (fu) __hip_atomic_fetch_or(&NF[v], fu, __ATOMIC_RELAXED, __HIP_MEMORY_SCOPE_WORKGROUP);
    if (fv) __hip_atomic_fetch_or(&NF[u], fv, __ATOMIC_RELAXED, __HIP_MEMORY_SCOPE_WORKGROUP);
}

// Merge the 8 NF copies; newly = nf & ~V; record popcount; advance frontier.
__global__ void node_update(u64* __restrict__ F, u64* __restrict__ NF8,
                            u64* __restrict__ V, u64* __restrict__ cnt,
                            int N, int depth) {
    int n = blockIdx.x * blockDim.x + threadIdx.x;
    if (n >= N) return;
    u64 nf = 0ull;
#pragma unroll
    for (int c = 0; c < NXCD; ++c) {
        nf |= NF8[(size_t)c * N + n];
        NF8[(size_t)c * N + n] = 0ull;
    }
    u64 vis = V[n];
    u64 newly = nf & ~vis;
    F[n] = newly;
    if (newly) {
        V[n] = vis | newly;
        cnt[n] += (u64)__popcll(newly) << (8 * depth);
    }
}

// Final level fused with output: merge NF copies -> c4, then
// out[n][:] = (sum_{d=0..4} c_d * E[d] + (nv - sum c_d) * E[5]) / nv
__global__ void node_last_finalize(const u64* __restrict__ NF8,
                                   const u64* __restrict__ V,
                                   const u64* __restrict__ cnt,
                                   const int* __restrict__ nvalid,
                                   const float* __restrict__ embed,
                                   float* __restrict__ out, int N, int D) {
    int n = blockIdx.x * blockDim.x + threadIdx.x;
    if (n >= N) return;
    u64 nf = 0ull;
#pragma unroll
    for (int c = 0; c < NXCD; ++c) nf |= NF8[(size_t)c * N + n];
    u64 vis = V[n];
    int c4 = __popcll(nf & ~vis);

    u64 c = cnt[n];
    int nv = *nvalid;
    float inv = 1.0f / (float)(nv > 0 ? nv : 1);
    float cd[MAXD + 1];
    int total = c4;
#pragma unroll
    for (int d = 0; d < 4; ++d) {
        int x = (int)((c >> (8 * d)) & 0xffull);
        total += x;
        cd[d] = (float)x;
    }
    cd[4] = (float)c4;
    cd[5] = (float)(nv - total);  // depth-5 + unreached

    float4* out4 = (float4*)(out + (size_t)n * D);
    const float4* e4 = (const float4*)embed;  // [6][4] float4 rows
#pragma unroll
    for (int q = 0; q < 4; ++q) {          // D == 16 -> 4 float4 per node
        float4 acc = {0.f, 0.f, 0.f, 0.f};
#pragma unroll
        for (int d = 0; d <= MAXD; ++d) {
            float4 e = e4[d * 4 + q];
            acc.x += cd[d] * e.x; acc.y += cd[d] * e.y;
            acc.z += cd[d] * e.z; acc.w += cd[d] * e.w;
        }
        acc.x *= inv; acc.y *= inv; acc.z *= inv; acc.w *= inv;
        out4[q] = acc;
    }
}

extern "C" void kernel_launch(void* const* d_in, const int* in_sizes, int n_in,
                              void* d_out, int out_size, void* d_ws, size_t ws_size,
                              hipStream_t stream) {
    const int*   h      = (const int*)d_in[0];
    const int*   t      = (const int*)d_in[1];
    const int*   anchor = (const int*)d_in[2];
    const float* embed  = (const float*)d_in[4];
    float*       out    = (float*)d_out;

    int E = in_sizes[0];
    int A = in_sizes[2];                 // 32 anchor triples -> K = 64 sources
    int D = in_sizes[4] / (MAXD + 1);    // 16
    int N = out_size / D;                // 50000

    u64* V   = (u64*)d_ws;
    u64* F   = V + N;
    u64* CNT = F + N;
    u64* NF8 = CNT + N;                  // 8 per-XCD copies
    int* nvalid = (int*)(NF8 + (size_t)NXCD * N);

    // d_ws is re-poisoned to 0xAA before every call -> zero all state.
    zero_ws<<<512, 256, 0, stream>>>((u64*)d_ws, (size_t)(3 + NXCD) * N);
    setup_sources<<<1, 64, 0, stream>>>(h, t, anchor, A, F, V, CNT, nvalid);

    int eb = (E + 255) / 256;
    int nb = (N + 255) / 256;
    for (int depth = 1; depth <= MAXD - 1; ++depth) {  // depth-5 folds into c5
        edge_prop<<<eb, 256, 0, stream>>>(h, t, F, NF8, N, E);
        if (depth < MAXD - 1) {
            node_update<<<nb, 256, 0, stream>>>(F, NF8, V, CNT, N, depth);
        } else {
            node_last_finalize<<<nb, 256, 0, stream>>>(NF8, V, CNT, nvalid,
                                                       embed, out, N, D);
        }
    }
}

// Round 3
// 152.248 us; speedup vs baseline: 1.4403x; 1.4164x over previous
//
#include <hip/hip_runtime.h>
#include <hip/hip_bf16.h>

typedef unsigned long long u64;
typedef unsigned int u32;

#define MAXD 5
#define BSH  6
#define BN   64          // nodes per bucket (LDS tile)
#define PAD  16          // u32 stride for contended counters (one 64B line each)
#define NW   128         // histogram/scatter workgroups

// ---------------------------------------------------------------------------
// Round-2 lesson: gfx950 global atomics write through to the memory side
// (32B/op) regardless of scope -> per-edge global atomicOr is the bottleneck.
// This version eliminates them: counting-sort edge-directions by dst-bucket
// (64 nodes), then each BFS level ORs frontier masks into an LDS-resident
// 64-node next-frontier tile (LDS atomics only); the owning workgroup writes
// V/CNT/F updates with plain stores. F is double-buffered across levels.
//
// ws layout: F0[N] V[N] CNT[N] F1[N] (u64) | countspad[NB*PAD] cursorspad[NB*PAD]
//            offs[NB+1] (u32) | nvalid (int) | recs[2E] (u32)
// ---------------------------------------------------------------------------

__global__ void zero_words(u32* __restrict__ p, size_t n) {
    size_t i = (size_t)blockIdx.x * blockDim.x + threadIdx.x;
    size_t stride = (size_t)gridDim.x * blockDim.x;
    for (; i < n; i += stride) p[i] = 0u;
}

// One wave. Gather 2*A anchor entities, dedup O(K^2), assign bit i per unique
// source, write initial F0/V/CNT + n_valid.
__global__ void setup_sources(const int* __restrict__ h, const int* __restrict__ t,
                              const int* __restrict__ anchor, int A,
                              u64* __restrict__ F, u64* __restrict__ V,
                              u64* __restrict__ cnt, int* __restrict__ nvalid) {
    __shared__ int ents[64];
    int i = threadIdx.x;
    int K = 2 * A;  // 64
    if (i < K) {
        int a = anchor[(i < A) ? i : (i - A)];
        ents[i] = (i < A) ? h[a] : t[a];
    }
    __syncthreads();
    bool uniq = false;
    int my = -1;
    if (i < K) {
        my = ents[i];
        uniq = true;
        for (int j = 0; j < i; ++j)
            if (ents[j] == my) { uniq = false; break; }
    }
    u64 mask = __ballot(uniq);
    if (i == 0) *nvalid = (int)__popcll(mask);
    if (uniq) {
        u64 bit = 1ull << i;
        F[my] = bit;     // unique ids -> distinct addresses -> plain stores ok
        V[my] = bit;
        cnt[my] = 1ull;  // depth-0 count (byte 0)
    }
}

// Per-bucket record counts. LDS-aggregated; merged with padded global atomics
// (NW per line, not per-edge).
__global__ void hist_kernel(const int* __restrict__ h, const int* __restrict__ t,
                            int E, u32* __restrict__ countspad, int NB) {
    extern __shared__ u32 lh[];
    for (int i = threadIdx.x; i < NB; i += blockDim.x) lh[i] = 0u;
    __syncthreads();
    int stride = gridDim.x * blockDim.x;
    for (int e = blockIdx.x * blockDim.x + threadIdx.x; e < E; e += stride) {
        u32 u = (u32)h[e], v = (u32)t[e];
        atomicAdd(&lh[v >> BSH], 1u);   // record (dst=v, src=u)
        atomicAdd(&lh[u >> BSH], 1u);   // record (dst=u, src=v)
    }
    __syncthreads();
    for (int i = threadIdx.x; i < NB; i += blockDim.x)
        if (lh[i]) atomicAdd(&countspad[i * PAD], lh[i]);
}

// Exclusive scan over NB bucket counts (single 1024-thread workgroup).
__global__ void scan_kernel(const u32* __restrict__ countspad, u32* __restrict__ offs,
                            u32* __restrict__ cursorspad, int NB) {
    __shared__ u32 s[1024];
    int i = threadIdx.x;
    u32 v = (i < NB) ? countspad[i * PAD] : 0u;
    s[i] = v;
    __syncthreads();
    for (int d = 1; d < 1024; d <<= 1) {
        u32 x = (i >= d) ? s[i - d] : 0u;
        __syncthreads();
        s[i] += x;
        __syncthreads();
    }
    u32 excl = s[i] - v;
    if (i < NB) { offs[i] = excl; cursorspad[i * PAD] = excl; }
    if (i == NB - 1) offs[NB] = s[i];
}

// Scatter edge-directions into bucketed record array.
// rec = (src << BSH) | (dst & (BN-1)); bucket implied by position.
__global__ void scatter_kernel(const int* __restrict__ h, const int* __restrict__ t,
                               int E, u32* __restrict__ cursorspad,
                               u32* __restrict__ recs, int NB) {
    extern __shared__ u32 sh[];      // lh[NB] | base[NB]
    u32* lh = sh;
    u32* base = sh + NB;
    for (int i = threadIdx.x; i < NB; i += blockDim.x) lh[i] = 0u;
    __syncthreads();
    int stride = gridDim.x * blockDim.x;
    int t0 = blockIdx.x * blockDim.x + threadIdx.x;
    for (int e = t0; e < E; e += stride) {
        u32 u = (u32)h[e], v = (u32)t[e];
        atomicAdd(&lh[v >> BSH], 1u);
        atomicAdd(&lh[u >> BSH], 1u);
    }
    __syncthreads();
    for (int i = threadIdx.x; i < NB; i += blockDim.x) {
        u32 c = lh[i];
        base[i] = c ? atomicAdd(&cursorspad[i * PAD], c) : 0u;
    }
    __syncthreads();
    for (int i = threadIdx.x; i < NB; i += blockDim.x) lh[i] = 0u;  // reuse as cursor
    __syncthreads();
    for (int e = t0; e < E; e += stride) {
        u32 u = (u32)h[e], v = (u32)t[e];
        u32 b1 = v >> BSH;
        u32 p1 = base[b1] + atomicAdd(&lh[b1], 1u);
        recs[p1] = (u << BSH) | (v & (BN - 1));
        u32 b2 = u >> BSH;
        u32 p2 = base[b2] + atomicAdd(&lh[b2], 1u);
        recs[p2] = (v << BSH) | (u & (BN - 1));
    }
}

// One BFS level: workgroup = one 64-node bucket. Gather F[src], OR into LDS
// tile, epilogue with plain stores (workgroup owns its node range).
__global__ void level_kernel(const u32* __restrict__ recs, const u32* __restrict__ offs,
                             const u64* __restrict__ Fin, u64* __restrict__ Fout,
                             u64* __restrict__ V, u64* __restrict__ CNT,
                             int N, int depth) {
    __shared__ u64 NF[BN];
    int b = blockIdx.x;
    if (threadIdx.x < BN) NF[threadIdx.x] = 0ull;
    __syncthreads();
    u32 s0 = offs[b], s1 = offs[b + 1];
    for (u32 r = s0 + threadIdx.x; r < s1; r += blockDim.x) {
        u32 rec = recs[r];
        u64 fu = Fin[rec >> BSH];
        if (fu) atomicOr(&NF[rec & (BN - 1)], fu);
    }
    __syncthreads();
    int tl = threadIdx.x;
    if (tl < BN) {
        int n = b * BN + tl;
        if (n < N) {
            u64 vis = V[n];
            u64 newly = NF[tl] & ~vis;
            Fout[n] = newly;
            if (newly) {
                V[n] = vis | newly;
                CNT[n] += (u64)__popcll(newly) << (8 * depth);
            }
        }
    }
}

// Final level fused with output: c4 from LDS tile, then
// out[n][:] = (sum_{d=0..4} c_d*E[d] + (nv - sum)*E[5]) / nv
__global__ void level4_finalize(const u32* __restrict__ recs, const u32* __restrict__ offs,
                                const u64* __restrict__ Fin, const u64* __restrict__ V,
                                const u64* __restrict__ CNT, const int* __restrict__ nvalid,
                                const float* __restrict__ embed, float* __restrict__ out,
                                int N, int D) {
    __shared__ u64 NF[BN];
    int b = blockIdx.x;
    if (threadIdx.x < BN) NF[threadIdx.x] = 0ull;
    __syncthreads();
    u32 s0 = offs[b], s1 = offs[b + 1];
    for (u32 r = s0 + threadIdx.x; r < s1; r += blockDim.x) {
        u32 rec = recs[r];
        u64 fu = Fin[rec >> BSH];
        if (fu) atomicOr(&NF[rec & (BN - 1)], fu);
    }
    __syncthreads();
    // 256 threads = 64 nodes x 4 float4 quads (D == 16)
    int tl = threadIdx.x;
    int nl = tl >> 2, q = tl & 3;
    int n = b * BN + nl;
    if (n >= N) return;
    u64 vis = V[n];
    int c4 = __popcll(NF[nl] & ~vis);
    u64 c = CNT[n];
    int nv = *nvalid;
    float inv = 1.0f / (float)(nv > 0 ? nv : 1);
    float cd[MAXD + 1];
    int total = c4;
#pragma unroll
    for (int d = 0; d < 4; ++d) {
        int x = (int)((c >> (8 * d)) & 0xffull);
        total += x;
        cd[d] = (float)x;
    }
    cd[4] = (float)c4;
    cd[5] = (float)(nv - total);  // depth-5 + unreached

    const float4* e4 = (const float4*)embed;  // [6][4] float4 rows
    float4 acc = {0.f, 0.f, 0.f, 0.f};
#pragma unroll
    for (int d = 0; d <= MAXD; ++d) {
        float4 e = e4[d * 4 + q];
        acc.x += cd[d] * e.x; acc.y += cd[d] * e.y;
        acc.z += cd[d] * e.z; acc.w += cd[d] * e.w;
    }
    acc.x *= inv; acc.y *= inv; acc.z *= inv; acc.w *= inv;
    ((float4*)(out + (size_t)n * D))[q] = acc;
}

extern "C" void kernel_launch(void* const* d_in, const int* in_sizes, int n_in,
                              void* d_out, int out_size, void* d_ws, size_t ws_size,
                              hipStream_t stream) {
    const int*   h      = (const int*)d_in[0];
    const int*   t      = (const int*)d_in[1];
    const int*   anchor = (const int*)d_in[2];
    const float* embed  = (const float*)d_in[4];
    float*       out    = (float*)d_out;

    int E = in_sizes[0];
    int A = in_sizes[2];              // 32 anchor triples -> K = 64 sources
    int D = in_sizes[4] / (MAXD + 1); // 16
    int N = out_size / D;             // 50000
    int NB = (N + BN - 1) >> BSH;     // 782 buckets (must be <= 1024 for scan)

    u64* F0  = (u64*)d_ws;
    u64* V   = F0 + N;
    u64* CNT = V + N;
    u64* F1  = CNT + N;
    u32* countspad  = (u32*)(F1 + N);
    u32* cursorspad = countspad + (size_t)NB * PAD;
    u32* offs       = cursorspad + (size_t)NB * PAD;
    int* nvalid     = (int*)(offs + NB + 1);
    u32* recs       = (u32*)(nvalid + 1);

    // Zero F0,V,CNT,F1,countspad,cursorspad,offs,nvalid in one sweep
    // (cursors/offs get overwritten by scan; F1 fully written by level1).
    size_t zwords = (size_t)8 * N + (size_t)2 * NB * PAD + (NB + 1) + 1;
    zero_words<<<512, 256, 0, stream>>>((u32*)d_ws, zwords);

    setup_sources<<<1, 64, 0, stream>>>(h, t, anchor, A, F0, V, CNT, nvalid);

    hist_kernel<<<NW, 256, NB * sizeof(u32), stream>>>(h, t, E, countspad, NB);
    scan_kernel<<<1, 1024, 0, stream>>>(countspad, offs, cursorspad, NB);
    scatter_kernel<<<NW, 256, 2 * NB * sizeof(u32), stream>>>(h, t, E, cursorspad, recs, NB);

    // Levels 1..3 (double-buffered F); level 4 fused with finalize.
    level_kernel<<<NB, 256, 0, stream>>>(recs, offs, F0, F1, V, CNT, N, 1);
    level_kernel<<<NB, 256, 0, stream>>>(recs, offs, F1, F0, V, CNT, N, 2);
    level_kernel<<<NB, 256, 0, stream>>>(recs, offs, F0, F1, V, CNT, N, 3);
    level4_finalize<<<NB, 256, 0, stream>>>(recs, offs, F1, V, CNT, nvalid,
                                            embed, out, N, D);
}